// Round 10
// baseline (3624.266 us; speedup 1.0000x reference)
//
#include <hip/hip_runtime.h>
#include <math.h>

namespace {

constexpr int   NT_   = 8;
constexpr int   NB_   = 12;
constexpr float TB_   = 5.0f;
constexpr float MINW_ = 0.001f;
constexpr float MINH_ = 0.001f;
constexpr float MIND_ = 0.001f;
constexpr float LOGZ_ = -2.7568155996140185f;  // -0.5*3*log(2*pi)

constexpr int PPP_   = 41;   // param-slab pitch
constexpr int WAVES_ = 4;    // fallback kernel only

// ---- mode F (fallback, == round-6 layout, 688128 B) ----
//  dense L in [0,32): L*4096 + swz(o,k) fp32 ; head at 131072 (fp32, 8*5120)
// ---- mode G (global-direct plane layout, 1032192 B) ----
//  dense b01: L*4096 + ct*1024 + ks*512 + half*256 + lane*4 + m   (packed p0|p1,
//             elem = half*4+m ; o = ct*16+(lane&15) ; k = ks*32+(lane>>4)*8+elem)
//  dense b2:  131072 + L*2048 + ct*512 + ks*256 + lane*4 + j      (pair-packed p2)
//  head b01:  196608 + i*5120 + ctg*1024 + ks*512 + half*256 + lane*4 + m
//  head b2:   237568 + i*2560 + ctg*512 + ks*256 + lane*4 + j
constexpr int WT_DENSE_F = 32 * 4096;              // 131072 dwords
constexpr int HEAD_FB    = WT_DENSE_F;             // mode-F head base
constexpr int WT_HEAD_F  = 8 * 5120;               // 40960 dwords
constexpr int PREP_TOT_F = WT_DENSE_F + WT_HEAD_F; // 172032 dwords

constexpr int P2B_       = 131072;                 // mode-G dense p2 base (dwords)
constexpr int WT_P2      = 32 * 2048;              // 65536 dwords
constexpr int HEAD_PB    = P2B_ + WT_P2;           // 196608 mode-G head b01 base
constexpr int HP2B_      = HEAD_PB + WT_HEAD_F;    // 237568 head p2 base
constexpr int WT_HP2     = 8 * 2560;               // 20480 dwords
constexpr int PREP_TOT_P = HP2B_ + WT_HP2;         // 258048 dwords
constexpr size_t WS_P_BYTES = (size_t)PREP_TOT_P * 4;  // 1032192

typedef __attribute__((ext_vector_type(8))) short        bf16x8;
typedef __attribute__((ext_vector_type(4))) float        f32x4;
typedef __attribute__((ext_vector_type(4))) unsigned int u32x4;

__device__ __forceinline__ float softplus_(float v) {
    return fmaxf(v, 0.0f) + log1pf(__expf(-fabsf(v)));
}

// Rational-quadratic spline, params in registers (verified in prior rounds).
__device__ __forceinline__ void rq_spline_reg(const float (&p)[37], float xr,
                                              float& y_out, float& lad_out) {
    float mw = -1e30f, mh = -1e30f;
#pragma unroll
    for (int q = 0; q < NB_; ++q) { mw = fmaxf(mw, p[q]); mh = fmaxf(mh, p[NB_ + q]); }

    float ew[NB_], eh[NB_];
    float sw = 0.0f, sh = 0.0f;
#pragma unroll
    for (int q = 0; q < NB_; ++q) { ew[q] = __expf(p[q] - mw);        sw += ew[q]; }
#pragma unroll
    for (int q = 0; q < NB_; ++q) { eh[q] = __expf(p[NB_ + q] - mh);  sh += eh[q]; }

    const float iw = (1.0f - MINW_ * (float)NB_) / sw;
    const float ih = (1.0f - MINH_ * (float)NB_) / sh;

    float cw[NB_ + 1], ch[NB_ + 1];
    cw[0] = -TB_; ch[0] = -TB_;
    float rw = 0.0f, rh = 0.0f;
#pragma unroll
    for (int q = 0; q < NB_; ++q) {
        rw += MINW_ + ew[q] * iw;
        rh += MINH_ + eh[q] * ih;
        cw[q + 1] = fmaf(2.0f * TB_, rw, -TB_);
        ch[q + 1] = fmaf(2.0f * TB_, rh, -TB_);
    }
    cw[NB_] = TB_;
    ch[NB_] = TB_;

    const float xc = fminf(fmaxf(xr, -TB_), TB_);

    int bi = 0;
#pragma unroll
    for (int q = 1; q <= NB_ - 1; ++q) bi += (xc >= cw[q]) ? 1 : 0;

    float in_cw = cw[0], cwn = cw[1], in_ch = ch[0], chn = ch[1];
    float udm1 = 0.0f, ud0 = p[24];
#pragma unroll
    for (int q = 1; q < NB_; ++q) {
        const bool s = (bi == q);
        in_cw = s ? cw[q]         : in_cw;
        cwn   = s ? cw[q + 1]     : cwn;
        in_ch = s ? ch[q]         : in_ch;
        chn   = s ? ch[q + 1]     : chn;
        udm1  = s ? p[24 + q - 1] : udm1;
        ud0   = s ? p[24 + q]     : ud0;
    }
    const float in_w = cwn - in_cw;
    const float in_h = chn - in_ch;
    const float d_k  = (bi == 0) ? 1.0f : (MIND_ + softplus_(udm1));
    const float d_k1 = MIND_ + softplus_(ud0);

    const float delta = in_h / in_w;
    const float theta = (xc - in_cw) / in_w;
    const float omt   = 1.0f - theta;
    const float t1m   = theta * omt;
    const float num   = in_h * (delta * theta * theta + d_k * t1m);
    const float den   = delta + (d_k + d_k1 - 2.0f * delta) * t1m;
    const float y     = in_ch + num / den;
    const float dnum  = delta * delta * (d_k1 * theta * theta + 2.0f * delta * t1m + d_k * omt * omt);
    const float lad   = __logf(dnum) - 2.0f * __logf(den);

    const bool inside = (xr >= -TB_) && (xr <= TB_);
    y_out   = inside ? y   : xr;
    lad_out = inside ? lad : 0.0f;
}

__device__ __forceinline__ float trunc16_(float x) {
    return __uint_as_float(__float_as_uint(x) & 0xFFFF0000u);
}
__device__ __forceinline__ unsigned hi16_(float x) { return __float_as_uint(x) >> 16; }

// head tile col -> W_out param index (ctg 2 = combined tile)
__device__ __forceinline__ int head_param_(int ctg, int c) {
    if (ctg < 2)  return ctg * 16 + c;
    if (ctg >= 3) return 37 + (ctg - 3) * 16 + c;
    if (c < 5)                 return 32 + c;
    if (c >= 8 && c < 13)      return 69 + (c - 8);
    return -1;
}

// ---- prep, mode F: dense + head -> fp32 o-major XOR-swizzled tiles ----
__global__ __launch_bounds__(256) void prep_F(const float* __restrict__ Wb,
                                              const float* __restrict__ Wo,
                                              float* __restrict__ wt) {
    const int t = blockIdx.x * 256 + threadIdx.x;
    if (t >= PREP_TOT_F) return;
    if (t < WT_DENSE_F) {
        const int L   = t >> 12;
        const int rem = t & 4095;
        const int o   = rem >> 6;
        const int q   = (rem >> 2) & 15;
        const int k   = ((q ^ (o & 15)) << 2) | (rem & 3);
        wt[t] = Wb[((size_t)L * 64 + o) * 64 + k];
    } else {
        const int t2  = t - WT_DENSE_F;
        const int i   = t2 / 5120;
        const int r1  = t2 - i * 5120;
        const int ctg = r1 >> 10;
        const int rem = r1 & 1023;
        const int c   = rem >> 6;
        const int q   = (rem >> 2) & 15;
        const int k   = ((q ^ c) << 2) | (rem & 3);
        const int param = head_param_(ctg, c);
        wt[t] = (param >= 0) ? Wo[((size_t)i * 74 + param) * 64 + k] : 0.0f;
    }
}

// ---- prep, mode G: fragment-linear packed b01 + pair-packed p2 (dense + head) ----
__global__ __launch_bounds__(256) void prep_G(const float* __restrict__ Wb,
                                              const float* __restrict__ Wo,
                                              float* __restrict__ wt) {
    const int t = blockIdx.x * 256 + threadIdx.x;
    if (t >= PREP_TOT_P) return;
    unsigned* wtu = (unsigned*)wt;
    if (t < WT_DENSE_F) {
        // dense b01 fragment-linear: (L, ct, ks, half, lane, m)
        const int L    = t >> 12;
        const int rem  = t & 4095;
        const int ct   = rem >> 10;
        const int r2   = rem & 1023;
        const int ks   = r2 >> 9;
        const int r3   = r2 & 511;
        const int half = r3 >> 8;
        const int r4   = r3 & 255;
        const int lane = r4 >> 2, m = r4 & 3;
        const int o    = ct * 16 + (lane & 15);
        const int k    = ks * 32 + (lane >> 4) * 8 + half * 4 + m;
        const float x  = Wb[((size_t)L * 64 + o) * 64 + k];
        wtu[t] = (hi16_(x) << 16) | hi16_(x - trunc16_(x));   // p0 HIGH, p1 LOW
    } else if (t < HEAD_PB) {
        // dense p2, pair-packed fragment-linear: (L, ct, ks, lane, j)
        const int t2   = t - P2B_;
        const int L    = t2 >> 11;
        const int rem  = t2 & 2047;
        const int g    = rem >> 8;          // ct*2 + ks
        const int ct   = g >> 1, ks = g & 1;
        const int r    = rem & 255;
        const int lane = r >> 2, j = r & 3;
        const int o    = ct * 16 + (lane & 15);
        const int kb   = 32 * ks + 8 * (lane >> 4) + 2 * j;
        const float x0 = Wb[((size_t)L * 64 + o) * 64 + kb];
        const float x1 = Wb[((size_t)L * 64 + o) * 64 + kb + 1];
        const float a0 = x0 - trunc16_(x0), b0 = a0 - trunc16_(a0);
        const float a1 = x1 - trunc16_(x1), b1 = a1 - trunc16_(a1);
        wtu[t] = (hi16_(b1) << 16) | hi16_(b0);    // even elem in low16
    } else if (t < HP2B_) {
        // head b01 fragment-linear: (i, ctg, ks, half, lane, m)
        const int t2   = t - HEAD_PB;
        const int i    = t2 / 5120;
        const int r1   = t2 - i * 5120;
        const int ctg  = r1 >> 10;
        const int r2   = r1 & 1023;
        const int ks   = r2 >> 9;
        const int r3   = r2 & 511;
        const int half = r3 >> 8;
        const int r4   = r3 & 255;
        const int lane = r4 >> 2, m = r4 & 3;
        const int c    = lane & 15;
        const int k    = ks * 32 + (lane >> 4) * 8 + half * 4 + m;
        const int param = head_param_(ctg, c);
        const float x = (param >= 0) ? Wo[((size_t)i * 74 + param) * 64 + k] : 0.0f;
        wtu[t] = (hi16_(x) << 16) | hi16_(x - trunc16_(x));
    } else {
        // head p2, pair-packed fragment-linear: (i, ctg, ks, lane, j)
        const int t2   = t - HP2B_;
        const int i    = t2 / 2560;
        const int r1   = t2 - i * 2560;
        const int ctg  = r1 >> 9;
        const int r2   = r1 & 511;
        const int ks   = r2 >> 8;
        const int r    = r2 & 255;
        const int lane = r >> 2, j = r & 3;
        const int c    = lane & 15;
        const int kb   = 32 * ks + 8 * (lane >> 4) + 2 * j;
        const int param = head_param_(ctg, c);
        float x0 = 0.0f, x1 = 0.0f;
        if (param >= 0) {
            x0 = Wo[((size_t)i * 74 + param) * 64 + kb];
            x1 = Wo[((size_t)i * 74 + param) * 64 + kb + 1];
        }
        const float a0 = x0 - trunc16_(x0), b0 = a0 - trunc16_(a0);
        const float a1 = x1 - trunc16_(x1), b1 = a1 - trunc16_(a1);
        wtu[t] = (hi16_(b1) << 16) | hi16_(b0);
    }
}

// ---- async stage NC 1024B chunks global->LDS (fallback kernel only) ----
template <int NC>
__device__ __forceinline__ void stage_(const float* __restrict__ g, float* lds,
                                       int wave, int wl) {
#pragma unroll
    for (int c = 0; c < (NC + WAVES_ - 1) / WAVES_; ++c) {
        const int cc = wave + WAVES_ * c;
        if (cc < NC) {
            __builtin_amdgcn_global_load_lds(
                (const __attribute__((address_space(1))) void*)(g + cc * 256 + wl * 4),
                (__attribute__((address_space(3))) void*)(lds + cc * 256), 16, 0, 0);
        }
    }
}

__device__ __forceinline__ f32x4 mfma16(u32x4 a, u32x4 b, f32x4 c) {
    return __builtin_amdgcn_mfma_f32_16x16x32_bf16(
        __builtin_bit_cast(bf16x8, a), __builtin_bit_cast(bf16x8, b), c, 0, 0, 0);
}

// pack top-16-bits of 8 floats into 4 dwords via v_perm (even elem -> low16)
__device__ __forceinline__ u32x4 packhi8(const float (&v)[8]) {
    u32x4 r;
    r.x = __builtin_amdgcn_perm(__float_as_uint(v[1]), __float_as_uint(v[0]), 0x07060302u);
    r.y = __builtin_amdgcn_perm(__float_as_uint(v[3]), __float_as_uint(v[2]), 0x07060302u);
    r.z = __builtin_amdgcn_perm(__float_as_uint(v[5]), __float_as_uint(v[4]), 0x07060302u);
    r.w = __builtin_amdgcn_perm(__float_as_uint(v[7]), __float_as_uint(v[6]), 0x07060302u);
    return r;
}

// x = s0 + s1 + s2 (truncated bf16 planes, rep err <= 2^-24 |x|)
__device__ __forceinline__ void split3_8(const float (&xv)[8],
                                         u32x4& f0, u32x4& f1, u32x4& f2) {
    float r1[8], r2[8];
#pragma unroll
    for (int j = 0; j < 8; ++j) r1[j] = xv[j] - trunc16_(xv[j]);
#pragma unroll
    for (int j = 0; j < 8; ++j) r2[j] = r1[j] - trunc16_(r1[j]);
    f0 = packhi8(xv);
    f1 = packhi8(r1);
    f2 = packhi8(r2);
}

// read 8 k-contiguous fp32 from a swizzled tile, split3
__device__ __forceinline__ void load3(const float* __restrict__ base, int tbase,
                                      int r1, int r2, u32x4& f0, u32x4& f1, u32x4& f2) {
    const f32x4 q0 = *(const f32x4*)&base[tbase + r1];
    const f32x4 q1 = *(const f32x4*)&base[tbase + r2];
    const float xv[8] = {q0.x, q0.y, q0.z, q0.w, q1.x, q1.y, q1.z, q1.w};
    split3_8(xv, f0, f1, f2);
}

// unpack b0 (hi16s) / b1 (lo16s) from 8 packed p0|p1 dwords in regs — 8 perms
__device__ __forceinline__ void unpack01r(const u32x4& d0, const u32x4& d1,
                                          u32x4& b0, u32x4& b1) {
    b0.x = __builtin_amdgcn_perm(d0.y, d0.x, 0x07060302u);
    b0.y = __builtin_amdgcn_perm(d0.w, d0.z, 0x07060302u);
    b0.z = __builtin_amdgcn_perm(d1.y, d1.x, 0x07060302u);
    b0.w = __builtin_amdgcn_perm(d1.w, d1.z, 0x07060302u);
    b1.x = __builtin_amdgcn_perm(d0.y, d0.x, 0x05040100u);
    b1.y = __builtin_amdgcn_perm(d0.w, d0.z, 0x05040100u);
    b1.z = __builtin_amdgcn_perm(d1.y, d1.x, 0x05040100u);
    b1.w = __builtin_amdgcn_perm(d1.w, d1.z, 0x05040100u);
}

__device__ __forceinline__ void loadA_all(const float* __restrict__ slab,
                                          const int (&R1v)[2], const int (&R2v)[2],
                                          u32x4 (&a0)[4][2], u32x4 (&a1)[4][2],
                                          u32x4 (&a2)[4][2]) {
#pragma unroll
    for (int ks = 0; ks < 2; ++ks)
#pragma unroll
        for (int rt = 0; rt < 4; ++rt)
            load3(slab, rt * 1024, R1v[ks], R2v[ks],
                  a0[rt][ks], a1[rt][ks], a2[rt][ks]);
}

__device__ __forceinline__ void chain6(const u32x4& A0, const u32x4& A1, const u32x4& A2,
                                       const u32x4& b0, const u32x4& b1, const u32x4& b2,
                                       f32x4& a) {
    a = mfma16(A0, b2, a);   // small terms first
    a = mfma16(A2, b0, a);
    a = mfma16(A1, b1, a);
    a = mfma16(A1, b0, a);
    a = mfma16(A0, b1, a);
    a = mfma16(A0, b0, a);
}

// mode F gemm tile: fp32 Ws + in-register split3 of B (fallback)
__device__ __forceinline__ void gemm_ct_F(const float* __restrict__ Ws, int ct,
                                          const u32x4 (&a0)[4][2], const u32x4 (&a1)[4][2],
                                          const u32x4 (&a2)[4][2],
                                          const int (&R1v)[2], const int (&R2v)[2],
                                          f32x4 (&acc)[4]) {
#pragma unroll
    for (int ks = 0; ks < 2; ++ks) {
        u32x4 b0, b1, b2;
        load3(Ws, ct * 1024, R1v[ks], R2v[ks], b0, b1, b2);
#pragma unroll
        for (int rt = 0; rt < 4; ++rt)
            chain6(a0[rt][ks], a1[rt][ks], a2[rt][ks], b0, b1, b2, acc[rt]);
    }
}

// mode G gemm tile: all 3 weight planes inline from global (L2-resident, coalesced).
// p01t/p2t include the lane*4 offset. 6 dwordx4 loads issued upfront (transient regs,
// single-tile live range — round-7 spill lesson); perms+MFMA cover the L2 latency.
__device__ __forceinline__ void gemm_ct_G(const unsigned* __restrict__ p01t,
                                          const unsigned* __restrict__ p2t,
                                          const u32x4 (&a0)[4][2], const u32x4 (&a1)[4][2],
                                          const u32x4 (&a2)[4][2],
                                          f32x4 (&acc)[4]) {
    u32x4 d0[2], d1[2], c2[2];
#pragma unroll
    for (int ks = 0; ks < 2; ++ks) {
        d0[ks] = *(const u32x4*)(p01t + ks * 512);
        d1[ks] = *(const u32x4*)(p01t + ks * 512 + 256);
        c2[ks] = *(const u32x4*)(p2t + ks * 256);
    }
#pragma unroll
    for (int ks = 0; ks < 2; ++ks) {
        u32x4 b0, b1;
        unpack01r(d0[ks], d1[ks], b0, b1);
#pragma unroll
        for (int rt = 0; rt < 4; ++rt)
            chain6(a0[rt][ks], a1[rt][ks], a2[rt][ks], b0, b1, c2[ks], acc[rt]);
    }
}

// ---- mode G dense layer (no LDS weights, no barriers) ----
template <bool RESID, bool RELU_OUT>
__device__ __forceinline__ void dense_layer_G(
    float* __restrict__ slab,
    const u32x4 (&a0)[4][2], const u32x4 (&a1)[4][2], const u32x4 (&a2)[4][2],
    const unsigned* __restrict__ p01,       // layer base, lane offset included
    const unsigned* __restrict__ p2,        // layer base, lane offset included
    const float* __restrict__ bias_g, float (&hreg)[4][4][4],
    const int (&K1)[4], const int (&K2)[4], int l15)
{
    float bly[4];
#pragma unroll
    for (int ct = 0; ct < 4; ++ct) bly[ct] = bias_g[ct * 16 + l15];
#pragma unroll
    for (int ct = 0; ct < 4; ++ct) {
        f32x4 acc[4];
#pragma unroll
        for (int rt = 0; rt < 4; ++rt) {
            if (RESID)
                acc[rt] = f32x4{hreg[rt][ct][0] + bly[ct], hreg[rt][ct][1] + bly[ct],
                                hreg[rt][ct][2] + bly[ct], hreg[rt][ct][3] + bly[ct]};
            else
                acc[rt] = f32x4{bly[ct], bly[ct], bly[ct], bly[ct]};
        }
        gemm_ct_G(p01 + ct * 1024, p2 + ct * 512, a0, a1, a2, acc);
#pragma unroll
        for (int rt = 0; rt < 4; ++rt) {
            if (RESID) {
#pragma unroll
                for (int r = 0; r < 4; ++r) hreg[rt][ct][r] = acc[rt][r];
            }
            const int base = rt * 1024 + K2[ct];
#pragma unroll
            for (int r = 0; r < 4; ++r) {
                const float v = RELU_OUT ? fmaxf(acc[rt][r], 0.0f) : acc[rt][r];
                slab[base + K1[r]] = v;
            }
        }
    }
}

// ---- h-init shared by both kernels ----
__device__ __forceinline__ void h_init_(int i, float ident, int l15, int lhi,
                                        const float* __restrict__ W_in,
                                        const float* __restrict__ b_in,
                                        u32x4 (&a0)[4][2], u32x4 (&a1)[4][2],
                                        u32x4 (&a2)[4][2], float (&hreg)[4][4][4]) {
    float idA[4], idD[4][4];
#pragma unroll
    for (int rt = 0; rt < 4; ++rt) idA[rt] = __shfl(ident, 16 * rt + l15, 64);
#pragma unroll
    for (int rt = 0; rt < 4; ++rt)
#pragma unroll
        for (int r = 0; r < 4; ++r)
            idD[rt][r] = __shfl(ident, 16 * rt + 4 * lhi + r, 64);
#pragma unroll
    for (int ks = 0; ks < 2; ++ks) {
        const int kb = i * 64 + 32 * ks + 8 * lhi;
        const f32x4 w0 = *(const f32x4*)&W_in[kb];
        const f32x4 w1 = *(const f32x4*)&W_in[kb + 4];
        const f32x4 c0 = *(const f32x4*)&b_in[kb];
        const f32x4 c1 = *(const f32x4*)&b_in[kb + 4];
        const float wv[8] = {w0.x, w0.y, w0.z, w0.w, w1.x, w1.y, w1.z, w1.w};
        const float bv[8] = {c0.x, c0.y, c0.z, c0.w, c1.x, c1.y, c1.z, c1.w};
#pragma unroll
        for (int rt = 0; rt < 4; ++rt) {
            float hx[8];
#pragma unroll
            for (int j = 0; j < 8; ++j)
                hx[j] = fmaxf(fmaf(idA[rt], wv[j], bv[j]), 0.0f);
            split3_8(hx, a0[rt][ks], a1[rt][ks], a2[rt][ks]);
        }
    }
#pragma unroll
    for (int ct = 0; ct < 4; ++ct) {
        const float wD = W_in[i * 64 + ct * 16 + l15];
        const float bD = b_in[i * 64 + ct * 16 + l15];
#pragma unroll
        for (int rt = 0; rt < 4; ++rt)
#pragma unroll
            for (int r = 0; r < 4; ++r)
                hreg[rt][ct][r] = fmaf(idD[rt][r], wD, bD);
    }
}

// ================== mode G kernel: 1 wave/block, ZERO barriers ==================
__global__ __launch_bounds__(64, 3) void nsf_g(
    const float* __restrict__ x,
    const float* __restrict__ W_in,  const float* __restrict__ b_in,
    const float* __restrict__ b_blk, const float* __restrict__ b_out,
    const float* __restrict__ wt,
    float* __restrict__ out, int n)
{
    __shared__ __align__(16) float slab[4096];   // 16 KB -> 10 blocks/CU

    const int wl  = threadIdx.x;   // 0..63
    const int l15 = wl & 15;
    const int lhi = wl >> 4;

    const int gidx = blockIdx.x * 64 + wl;
    const int idx  = gidx < n ? gidx : (n - 1);

    float z0 = x[3 * idx + 0];
    float z1 = x[3 * idx + 1];
    float z2 = x[3 * idx + 2];
    float lad_total = 0.0f;

    // lane-constant addresses. slab dword(p,k) = p*64 + ((k>>2 ^ (p&15))<<2) + (k&3)
    int K1[4], K2[4], R1v[2], R2v[2], P1[4];
#pragma unroll
    for (int r = 0; r < 4; ++r)
        K1[r] = (4 * lhi + r) * 64 + ((((l15 >> 2) ^ r)) << 2) + (l15 & 3);
#pragma unroll
    for (int c = 0; c < 4; ++c) K2[c] = (c ^ lhi) << 4;
#pragma unroll
    for (int s = 0; s < 2; ++s) {
        const int c0 = 8 * s + 2 * lhi;
        R1v[s] = l15 * 64 + ((c0 ^ l15) << 2);
        R2v[s] = l15 * 64 + (((c0 + 1) ^ l15) << 2);
    }
#pragma unroll
    for (int r = 0; r < 4; ++r) P1[r] = (4 * lhi + r) * PPP_ + l15;

    // global weight-plane bases for this lane
    const unsigned* b01w  = (const unsigned*)wt +           wl * 4;
    const unsigned* p2w   = (const unsigned*)wt + P2B_    + wl * 4;
    const unsigned* hb01w = (const unsigned*)wt + HEAD_PB + wl * 4;
    const unsigned* hp2w  = (const unsigned*)wt + HP2B_   + wl * 4;

#pragma unroll 1
    for (int i = 0; i < NT_; ++i) {
        const float ident = z2, tr0 = z1, tr1 = z0;

        u32x4 a0[4][2], a1[4][2], a2[4][2];
        float hreg[4][4][4];
        h_init_(i, ident, l15, lhi, W_in, b_in, a0, a1, a2, hreg);

        // G1..G4, no barriers: slab is wave-private; weights stream from L2
        dense_layer_G<false, true>(slab, a0, a1, a2,
                                   b01w + (size_t)(i * 4 + 0) * 4096,
                                   p2w  + (size_t)(i * 4 + 0) * 2048,
                                   b_blk + (size_t)(i * 4 + 0) * 64, hreg, K1, K2, l15);
        loadA_all(slab, R1v, R2v, a0, a1, a2);               // A2 = relu(t1)
        dense_layer_G<true, true>(slab, a0, a1, a2,
                                  b01w + (size_t)(i * 4 + 1) * 4096,
                                  p2w  + (size_t)(i * 4 + 1) * 2048,
                                  b_blk + (size_t)(i * 4 + 1) * 64, hreg, K1, K2, l15);
        loadA_all(slab, R1v, R2v, a0, a1, a2);               // A3 = relu(h1)
        dense_layer_G<false, true>(slab, a0, a1, a2,
                                   b01w + (size_t)(i * 4 + 2) * 4096,
                                   p2w  + (size_t)(i * 4 + 2) * 2048,
                                   b_blk + (size_t)(i * 4 + 2) * 64, hreg, K1, K2, l15);
        loadA_all(slab, R1v, R2v, a0, a1, a2);               // A4 = relu(t3)
        dense_layer_G<true, false>(slab, a0, a1, a2,
                                   b01w + (size_t)(i * 4 + 3) * 4096,
                                   p2w  + (size_t)(i * 4 + 3) * 2048,
                                   b_blk + (size_t)(i * 4 + 3) * 64, hreg, K1, K2, l15);
        loadA_all(slab, R1v, R2v, a0, a1, a2);               // A5 = raw h2

        const unsigned* hb01 = hb01w + (size_t)i * 5120;
        const unsigned* hp2  = hp2w  + (size_t)i * 2560;

        // ---- head half 0: ct0, ct1 -> params; comb (ctg2) -> regs ----
        f32x4 combD[4];
#pragma unroll
        for (int ct = 0; ct < 3; ++ct) {
            f32x4 acc[4];
#pragma unroll
            for (int rt = 0; rt < 4; ++rt) acc[rt] = f32x4{0.f, 0.f, 0.f, 0.f};
            gemm_ct_G(hb01 + ct * 1024, hp2 + ct * 512, a0, a1, a2, acc);
            if (ct < 2) {
#pragma unroll
                for (int rt = 0; rt < 4; ++rt)
#pragma unroll
                    for (int r = 0; r < 4; ++r)
                        slab[rt * 656 + P1[r] + 16 * ct] = acc[rt][r];
            } else {
#pragma unroll
                for (int rt = 0; rt < 4; ++rt) combD[rt] = acc[rt];
                if (l15 < 5) {
#pragma unroll
                    for (int rt = 0; rt < 4; ++rt)
#pragma unroll
                        for (int r = 0; r < 4; ++r)
                            slab[rt * 656 + P1[r] + 32] = acc[rt][r];
                }
            }
        }

        const float* bo = b_out + i * 74;
        float y0, l0v, y1, l1v;
        {
            float p0[37];
#pragma unroll
            for (int q = 0; q < 37; ++q) p0[q] = slab[wl * PPP_ + q] + bo[q];
            rq_spline_reg(p0, tr0, y0, l0v);
        }

        // ---- head half 1: ctg 3,4 + saved comb cols ----
#pragma unroll
        for (int ct = 0; ct < 2; ++ct) {
            f32x4 acc[4];
#pragma unroll
            for (int rt = 0; rt < 4; ++rt) acc[rt] = f32x4{0.f, 0.f, 0.f, 0.f};
            gemm_ct_G(hb01 + (3 + ct) * 1024, hp2 + (3 + ct) * 512, a0, a1, a2, acc);
#pragma unroll
            for (int rt = 0; rt < 4; ++rt)
#pragma unroll
                for (int r = 0; r < 4; ++r)
                    slab[rt * 656 + P1[r] + 16 * ct] = acc[rt][r];
        }
        if (l15 >= 8 && l15 < 13) {
#pragma unroll
            for (int rt = 0; rt < 4; ++rt)
#pragma unroll
                for (int r = 0; r < 4; ++r)
                    slab[rt * 656 + P1[r] + 24] = combD[rt][r];  // q = 32 + (l15-8)
        }
        {
            float p1[37];
#pragma unroll
            for (int q = 0; q < 37; ++q) p1[q] = slab[wl * PPP_ + q] + bo[37 + q];
            rq_spline_reg(p1, tr1, y1, l1v);
        }

        lad_total += l0v + l1v;
        z0 = ident;
        z1 = y0;
        z2 = y1;
    }

    if (gidx < n)
        out[gidx] = -0.5f * (z0 * z0 + z1 * z1 + z2 * z2) + LOGZ_ + lad_total;
}

// ================== mode F fallback kernel (round-9 P=false, verbatim) ==================
template <bool RESID, bool RELU_OUT>
__device__ __forceinline__ void dense_layer_F(
    float* __restrict__ slab, const float* __restrict__ Ws,
    const u32x4 (&a0)[4][2], const u32x4 (&a1)[4][2], const u32x4 (&a2)[4][2],
    const int (&R1v)[2], const int (&R2v)[2],
    const float* __restrict__ bias_g, float (&hreg)[4][4][4],
    const int (&K1)[4], const int (&K2)[4], int l15)
{
    float bly[4];
#pragma unroll
    for (int ct = 0; ct < 4; ++ct) bly[ct] = bias_g[ct * 16 + l15];
#pragma unroll
    for (int ct = 0; ct < 4; ++ct) {
        f32x4 acc[4];
#pragma unroll
        for (int rt = 0; rt < 4; ++rt) {
            if (RESID)
                acc[rt] = f32x4{hreg[rt][ct][0] + bly[ct], hreg[rt][ct][1] + bly[ct],
                                hreg[rt][ct][2] + bly[ct], hreg[rt][ct][3] + bly[ct]};
            else
                acc[rt] = f32x4{bly[ct], bly[ct], bly[ct], bly[ct]};
        }
        gemm_ct_F(Ws, ct, a0, a1, a2, R1v, R2v, acc);
#pragma unroll
        for (int rt = 0; rt < 4; ++rt) {
            if (RESID) {
#pragma unroll
                for (int r = 0; r < 4; ++r) hreg[rt][ct][r] = acc[rt][r];
            }
            const int base = rt * 1024 + K2[ct];
#pragma unroll
            for (int r = 0; r < 4; ++r) {
                const float v = RELU_OUT ? fmaxf(acc[rt][r], 0.0f) : acc[rt][r];
                slab[base + K1[r]] = v;
            }
        }
    }
}

__global__ __launch_bounds__(256, 2) void nsf_f(
    const float* __restrict__ x,
    const float* __restrict__ W_in,  const float* __restrict__ b_in,
    const float* __restrict__ b_blk, const float* __restrict__ b_out,
    const float* __restrict__ wt,
    float* __restrict__ out, int n)
{
    __shared__ __align__(16) float As2[WAVES_ * 4096];
    __shared__ __align__(16) float Ws[4096];

    const int l    = threadIdx.x;
    const int wave = l >> 6;
    const int wl   = l & 63;
    const int l15  = wl & 15;
    const int lhi  = wl >> 4;
    float* slab = As2 + wave * 4096;

    const int gidx = blockIdx.x * 256 + l;
    const int idx  = gidx < n ? gidx : (n - 1);

    float z0 = x[3 * idx + 0];
    float z1 = x[3 * idx + 1];
    float z2 = x[3 * idx + 2];
    float lad_total = 0.0f;

    int K1[4], K2[4], R1v[2], R2v[2], P1[4];
#pragma unroll
    for (int r = 0; r < 4; ++r)
        K1[r] = (4 * lhi + r) * 64 + ((((l15 >> 2) ^ r)) << 2) + (l15 & 3);
#pragma unroll
    for (int c = 0; c < 4; ++c) K2[c] = (c ^ lhi) << 4;
#pragma unroll
    for (int s = 0; s < 2; ++s) {
        const int c0 = 8 * s + 2 * lhi;
        R1v[s] = l15 * 64 + ((c0 ^ l15) << 2);
        R2v[s] = l15 * 64 + (((c0 + 1) ^ l15) << 2);
    }
#pragma unroll
    for (int r = 0; r < 4; ++r) P1[r] = (4 * lhi + r) * PPP_ + l15;

    stage_<16>(wt, Ws, wave, wl);
    __syncthreads();

#pragma unroll 1
    for (int i = 0; i < NT_; ++i) {
        const float ident = z2, tr0 = z1, tr1 = z0;

        u32x4 a0[4][2], a1[4][2], a2[4][2];
        float hreg[4][4][4];
        h_init_(i, ident, l15, lhi, W_in, b_in, a0, a1, a2, hreg);

        dense_layer_F<false, true>(slab, Ws, a0, a1, a2, R1v, R2v,
                                   b_blk + (size_t)(i * 4 + 0) * 64, hreg, K1, K2, l15);
        __syncthreads();
        stage_<16>(wt + (size_t)(i * 4 + 1) * 4096, Ws, wave, wl);
        loadA_all(slab, R1v, R2v, a0, a1, a2);
        __syncthreads();

        dense_layer_F<true, true>(slab, Ws, a0, a1, a2, R1v, R2v,
                                  b_blk + (size_t)(i * 4 + 1) * 64, hreg, K1, K2, l15);
        __syncthreads();
        stage_<16>(wt + (size_t)(i * 4 + 2) * 4096, Ws, wave, wl);
        loadA_all(slab, R1v, R2v, a0, a1, a2);
        __syncthreads();

        dense_layer_F<false, true>(slab, Ws, a0, a1, a2, R1v, R2v,
                                   b_blk + (size_t)(i * 4 + 2) * 64, hreg, K1, K2, l15);
        __syncthreads();
        stage_<16>(wt + (size_t)(i * 4 + 3) * 4096, Ws, wave, wl);
        loadA_all(slab, R1v, R2v, a0, a1, a2);
        __syncthreads();

        dense_layer_F<true, false>(slab, Ws, a0, a1, a2, R1v, R2v,
                                   b_blk + (size_t)(i * 4 + 3) * 64, hreg, K1, K2, l15);
        __syncthreads();
        stage_<12>(wt + HEAD_FB + (size_t)i * 5120, Ws, wave, wl);
        loadA_all(slab, R1v, R2v, a0, a1, a2);
        __syncthreads();

        f32x4 combD[4];
#pragma unroll
        for (int ct = 0; ct < 3; ++ct) {
            f32x4 acc[4];
#pragma unroll
            for (int rt = 0; rt < 4; ++rt) acc[rt] = f32x4{0.f, 0.f, 0.f, 0.f};
            gemm_ct_F(Ws, ct, a0, a1, a2, R1v, R2v, acc);
            if (ct < 2) {
#pragma unroll
                for (int rt = 0; rt < 4; ++rt)
#pragma unroll
                    for (int r = 0; r < 4; ++r)
                        slab[rt * 656 + P1[r] + 16 * ct] = acc[rt][r];
            } else {
#pragma unroll
                for (int rt = 0; rt < 4; ++rt) combD[rt] = acc[rt];
                if (l15 < 5) {
#pragma unroll
                    for (int rt = 0; rt < 4; ++rt)
#pragma unroll
                        for (int r = 0; r < 4; ++r)
                            slab[rt * 656 + P1[r] + 32] = acc[rt][r];
                }
            }
        }
        __syncthreads();
        stage_<8>(wt + HEAD_FB + (size_t)i * 5120 + 3072, Ws, wave, wl);

        const float* bo = b_out + i * 74;
        float y0, l0v, y1, l1v;
        {
            float p0[37];
#pragma unroll
            for (int q = 0; q < 37; ++q) p0[q] = slab[wl * PPP_ + q] + bo[q];
            rq_spline_reg(p0, tr0, y0, l0v);
        }
        __syncthreads();

#pragma unroll
        for (int ct = 0; ct < 2; ++ct) {
            f32x4 acc[4];
#pragma unroll
            for (int rt = 0; rt < 4; ++rt) acc[rt] = f32x4{0.f, 0.f, 0.f, 0.f};
            gemm_ct_F(Ws, ct, a0, a1, a2, R1v, R2v, acc);
#pragma unroll
            for (int rt = 0; rt < 4; ++rt)
#pragma unroll
                for (int r = 0; r < 4; ++r)
                    slab[rt * 656 + P1[r] + 16 * ct] = acc[rt][r];
        }
        if (l15 >= 8 && l15 < 13) {
#pragma unroll
            for (int rt = 0; rt < 4; ++rt)
#pragma unroll
                for (int r = 0; r < 4; ++r)
                    slab[rt * 656 + P1[r] + 24] = combD[rt][r];
        }
        __syncthreads();
        if (i < NT_ - 1) stage_<16>(wt + (size_t)((i + 1) * 4) * 4096, Ws, wave, wl);
        {
            float p1[37];
#pragma unroll
            for (int q = 0; q < 37; ++q) p1[q] = slab[wl * PPP_ + q] + bo[37 + q];
            rq_spline_reg(p1, tr1, y1, l1v);
        }
        __syncthreads();

        lad_total += l0v + l1v;
        z0 = ident;
        z1 = y0;
        z2 = y1;
    }

    if (gidx < n)
        out[gidx] = -0.5f * (z0 * z0 + z1 * z1 + z2 * z2) + LOGZ_ + lad_total;
}

}  // namespace

extern "C" void kernel_launch(void* const* d_in, const int* in_sizes, int n_in,
                              void* d_out, int out_size, void* d_ws, size_t ws_size,
                              hipStream_t stream) {
    const float* x     = (const float*)d_in[0];
    const float* W_in  = (const float*)d_in[1];
    const float* b_in  = (const float*)d_in[2];
    const float* W_blk = (const float*)d_in[3];
    const float* b_blk = (const float*)d_in[4];
    const float* W_out = (const float*)d_in[5];
    const float* b_out = (const float*)d_in[6];
    float* out = (float*)d_out;

    const int n = in_sizes[0] / 3;

    if (ws_size >= WS_P_BYTES) {
        prep_G<<<(PREP_TOT_P + 255) / 256, 256, 0, stream>>>(
            W_blk, W_out, (float*)d_ws);
        const int grid = (n + 63) / 64;
        nsf_g<<<grid, 64, 0, stream>>>(x, W_in, b_in, b_blk, b_out,
                                       (const float*)d_ws, out, n);
    } else {
        prep_F<<<(PREP_TOT_F + 255) / 256, 256, 0, stream>>>(
            W_blk, W_out, (float*)d_ws);
        const int grid = (n + 255) / 256;
        nsf_f<<<grid, 256, 0, stream>>>(x, W_in, b_in, b_blk, b_out,
                                        (const float*)d_ws, out, n);
    }
}

// Round 11
// 1865.734 us; speedup vs baseline: 1.9425x; 1.9425x over previous
//
#include <hip/hip_runtime.h>
#include <math.h>

namespace {

constexpr int   NT_   = 8;
constexpr int   NB_   = 12;
constexpr float TB_   = 5.0f;
constexpr float MINW_ = 0.001f;
constexpr float MINH_ = 0.001f;
constexpr float MIND_ = 0.001f;
constexpr float LOGZ_ = -2.7568155996140185f;  // -0.5*3*log(2*pi)

constexpr int PPP_   = 41;   // param-slab pitch
constexpr int WAVES_ = 4;    // fallback kernel only

// ---- mode F (fallback, == round-6 layout, 688128 B) ----
//  dense L in [0,32): L*4096 + swz(o,k) fp32 ; head at 131072 (fp32, 8*5120)
// ---- mode G (global-direct plane layout, 1032192 B) ----
//  dense b01: L*4096 + ct*1024 + ks*512 + half*256 + lane*4 + m   (packed p0|p1,
//             elem = half*4+m ; o = ct*16+(lane&15) ; k = ks*32+(lane>>4)*8+elem)
//  dense b2:  131072 + L*2048 + ct*512 + ks*256 + lane*4 + j      (pair-packed p2)
//  head b01:  196608 + i*5120 + ctg*1024 + ks*512 + half*256 + lane*4 + m
//  head b2:   237568 + i*2560 + ctg*512 + ks*256 + lane*4 + j
constexpr int WT_DENSE_F = 32 * 4096;              // 131072 dwords
constexpr int HEAD_FB    = WT_DENSE_F;             // mode-F head base
constexpr int WT_HEAD_F  = 8 * 5120;               // 40960 dwords
constexpr int PREP_TOT_F = WT_DENSE_F + WT_HEAD_F; // 172032 dwords

constexpr int P2B_       = 131072;                 // mode-G dense p2 base (dwords)
constexpr int WT_P2      = 32 * 2048;              // 65536 dwords
constexpr int HEAD_PB    = P2B_ + WT_P2;           // 196608 mode-G head b01 base
constexpr int HP2B_      = HEAD_PB + WT_HEAD_F;    // 237568 head p2 base
constexpr int WT_HP2     = 8 * 2560;               // 20480 dwords
constexpr int PREP_TOT_P = HP2B_ + WT_HP2;         // 258048 dwords
constexpr size_t WS_P_BYTES = (size_t)PREP_TOT_P * 4;  // 1032192

typedef __attribute__((ext_vector_type(8))) short        bf16x8;
typedef __attribute__((ext_vector_type(4))) float        f32x4;
typedef __attribute__((ext_vector_type(4))) unsigned int u32x4;

__device__ __forceinline__ float softplus_(float v) {
    return fmaxf(v, 0.0f) + log1pf(__expf(-fabsf(v)));
}

// Rational-quadratic spline, params in registers (verified in prior rounds).
__device__ __forceinline__ void rq_spline_reg(const float (&p)[37], float xr,
                                              float& y_out, float& lad_out) {
    float mw = -1e30f, mh = -1e30f;
#pragma unroll
    for (int q = 0; q < NB_; ++q) { mw = fmaxf(mw, p[q]); mh = fmaxf(mh, p[NB_ + q]); }

    float ew[NB_], eh[NB_];
    float sw = 0.0f, sh = 0.0f;
#pragma unroll
    for (int q = 0; q < NB_; ++q) { ew[q] = __expf(p[q] - mw);        sw += ew[q]; }
#pragma unroll
    for (int q = 0; q < NB_; ++q) { eh[q] = __expf(p[NB_ + q] - mh);  sh += eh[q]; }

    const float iw = (1.0f - MINW_ * (float)NB_) / sw;
    const float ih = (1.0f - MINH_ * (float)NB_) / sh;

    float cw[NB_ + 1], ch[NB_ + 1];
    cw[0] = -TB_; ch[0] = -TB_;
    float rw = 0.0f, rh = 0.0f;
#pragma unroll
    for (int q = 0; q < NB_; ++q) {
        rw += MINW_ + ew[q] * iw;
        rh += MINH_ + eh[q] * ih;
        cw[q + 1] = fmaf(2.0f * TB_, rw, -TB_);
        ch[q + 1] = fmaf(2.0f * TB_, rh, -TB_);
    }
    cw[NB_] = TB_;
    ch[NB_] = TB_;

    const float xc = fminf(fmaxf(xr, -TB_), TB_);

    int bi = 0;
#pragma unroll
    for (int q = 1; q <= NB_ - 1; ++q) bi += (xc >= cw[q]) ? 1 : 0;

    float in_cw = cw[0], cwn = cw[1], in_ch = ch[0], chn = ch[1];
    float udm1 = 0.0f, ud0 = p[24];
#pragma unroll
    for (int q = 1; q < NB_; ++q) {
        const bool s = (bi == q);
        in_cw = s ? cw[q]         : in_cw;
        cwn   = s ? cw[q + 1]     : cwn;
        in_ch = s ? ch[q]         : in_ch;
        chn   = s ? ch[q + 1]     : chn;
        udm1  = s ? p[24 + q - 1] : udm1;
        ud0   = s ? p[24 + q]     : ud0;
    }
    const float in_w = cwn - in_cw;
    const float in_h = chn - in_ch;
    const float d_k  = (bi == 0) ? 1.0f : (MIND_ + softplus_(udm1));
    const float d_k1 = MIND_ + softplus_(ud0);

    const float delta = in_h / in_w;
    const float theta = (xc - in_cw) / in_w;
    const float omt   = 1.0f - theta;
    const float t1m   = theta * omt;
    const float num   = in_h * (delta * theta * theta + d_k * t1m);
    const float den   = delta + (d_k + d_k1 - 2.0f * delta) * t1m;
    const float y     = in_ch + num / den;
    const float dnum  = delta * delta * (d_k1 * theta * theta + 2.0f * delta * t1m + d_k * omt * omt);
    const float lad   = __logf(dnum) - 2.0f * __logf(den);

    const bool inside = (xr >= -TB_) && (xr <= TB_);
    y_out   = inside ? y   : xr;
    lad_out = inside ? lad : 0.0f;
}

__device__ __forceinline__ float trunc16_(float x) {
    return __uint_as_float(__float_as_uint(x) & 0xFFFF0000u);
}
__device__ __forceinline__ unsigned hi16_(float x) { return __float_as_uint(x) >> 16; }

// head tile col -> W_out param index (ctg 2 = combined tile)
__device__ __forceinline__ int head_param_(int ctg, int c) {
    if (ctg < 2)  return ctg * 16 + c;
    if (ctg >= 3) return 37 + (ctg - 3) * 16 + c;
    if (c < 5)                 return 32 + c;
    if (c >= 8 && c < 13)      return 69 + (c - 8);
    return -1;
}

// ---- prep, mode F: dense + head -> fp32 o-major XOR-swizzled tiles ----
__global__ __launch_bounds__(256) void prep_F(const float* __restrict__ Wb,
                                              const float* __restrict__ Wo,
                                              float* __restrict__ wt) {
    const int t = blockIdx.x * 256 + threadIdx.x;
    if (t >= PREP_TOT_F) return;
    if (t < WT_DENSE_F) {
        const int L   = t >> 12;
        const int rem = t & 4095;
        const int o   = rem >> 6;
        const int q   = (rem >> 2) & 15;
        const int k   = ((q ^ (o & 15)) << 2) | (rem & 3);
        wt[t] = Wb[((size_t)L * 64 + o) * 64 + k];
    } else {
        const int t2  = t - WT_DENSE_F;
        const int i   = t2 / 5120;
        const int r1  = t2 - i * 5120;
        const int ctg = r1 >> 10;
        const int rem = r1 & 1023;
        const int c   = rem >> 6;
        const int q   = (rem >> 2) & 15;
        const int k   = ((q ^ c) << 2) | (rem & 3);
        const int param = head_param_(ctg, c);
        wt[t] = (param >= 0) ? Wo[((size_t)i * 74 + param) * 64 + k] : 0.0f;
    }
}

// ---- prep, mode G: fragment-linear packed b01 + pair-packed p2 (dense + head) ----
__global__ __launch_bounds__(256) void prep_G(const float* __restrict__ Wb,
                                              const float* __restrict__ Wo,
                                              float* __restrict__ wt) {
    const int t = blockIdx.x * 256 + threadIdx.x;
    if (t >= PREP_TOT_P) return;
    unsigned* wtu = (unsigned*)wt;
    if (t < WT_DENSE_F) {
        // dense b01 fragment-linear: (L, ct, ks, half, lane, m)
        const int L    = t >> 12;
        const int rem  = t & 4095;
        const int ct   = rem >> 10;
        const int r2   = rem & 1023;
        const int ks   = r2 >> 9;
        const int r3   = r2 & 511;
        const int half = r3 >> 8;
        const int r4   = r3 & 255;
        const int lane = r4 >> 2, m = r4 & 3;
        const int o    = ct * 16 + (lane & 15);
        const int k    = ks * 32 + (lane >> 4) * 8 + half * 4 + m;
        const float x  = Wb[((size_t)L * 64 + o) * 64 + k];
        wtu[t] = (hi16_(x) << 16) | hi16_(x - trunc16_(x));   // p0 HIGH, p1 LOW
    } else if (t < HEAD_PB) {
        // dense p2, pair-packed fragment-linear: (L, ct, ks, lane, j)
        const int t2   = t - P2B_;
        const int L    = t2 >> 11;
        const int rem  = t2 & 2047;
        const int g    = rem >> 8;          // ct*2 + ks
        const int ct   = g >> 1, ks = g & 1;
        const int r    = rem & 255;
        const int lane = r >> 2, j = r & 3;
        const int o    = ct * 16 + (lane & 15);
        const int kb   = 32 * ks + 8 * (lane >> 4) + 2 * j;
        const float x0 = Wb[((size_t)L * 64 + o) * 64 + kb];
        const float x1 = Wb[((size_t)L * 64 + o) * 64 + kb + 1];
        const float a0 = x0 - trunc16_(x0), b0 = a0 - trunc16_(a0);
        const float a1 = x1 - trunc16_(x1), b1 = a1 - trunc16_(a1);
        wtu[t] = (hi16_(b1) << 16) | hi16_(b0);    // even elem in low16
    } else if (t < HP2B_) {
        // head b01 fragment-linear: (i, ctg, ks, half, lane, m)
        const int t2   = t - HEAD_PB;
        const int i    = t2 / 5120;
        const int r1   = t2 - i * 5120;
        const int ctg  = r1 >> 10;
        const int r2   = r1 & 1023;
        const int ks   = r2 >> 9;
        const int r3   = r2 & 511;
        const int half = r3 >> 8;
        const int r4   = r3 & 255;
        const int lane = r4 >> 2, m = r4 & 3;
        const int c    = lane & 15;
        const int k    = ks * 32 + (lane >> 4) * 8 + half * 4 + m;
        const int param = head_param_(ctg, c);
        const float x = (param >= 0) ? Wo[((size_t)i * 74 + param) * 64 + k] : 0.0f;
        wtu[t] = (hi16_(x) << 16) | hi16_(x - trunc16_(x));
    } else {
        // head p2, pair-packed fragment-linear: (i, ctg, ks, lane, j)
        const int t2   = t - HP2B_;
        const int i    = t2 / 2560;
        const int r1   = t2 - i * 2560;
        const int ctg  = r1 >> 9;
        const int r2   = r1 & 511;
        const int ks   = r2 >> 8;
        const int r    = r2 & 255;
        const int lane = r >> 2, j = r & 3;
        const int c    = lane & 15;
        const int kb   = 32 * ks + 8 * (lane >> 4) + 2 * j;
        const int param = head_param_(ctg, c);
        float x0 = 0.0f, x1 = 0.0f;
        if (param >= 0) {
            x0 = Wo[((size_t)i * 74 + param) * 64 + kb];
            x1 = Wo[((size_t)i * 74 + param) * 64 + kb + 1];
        }
        const float a0 = x0 - trunc16_(x0), b0 = a0 - trunc16_(a0);
        const float a1 = x1 - trunc16_(x1), b1 = a1 - trunc16_(a1);
        wtu[t] = (hi16_(b1) << 16) | hi16_(b0);
    }
}

// ---- async stage NC 1024B chunks global->LDS (fallback kernel only) ----
template <int NC>
__device__ __forceinline__ void stage_(const float* __restrict__ g, float* lds,
                                       int wave, int wl) {
#pragma unroll
    for (int c = 0; c < (NC + WAVES_ - 1) / WAVES_; ++c) {
        const int cc = wave + WAVES_ * c;
        if (cc < NC) {
            __builtin_amdgcn_global_load_lds(
                (const __attribute__((address_space(1))) void*)(g + cc * 256 + wl * 4),
                (__attribute__((address_space(3))) void*)(lds + cc * 256), 16, 0, 0);
        }
    }
}

__device__ __forceinline__ f32x4 mfma16(u32x4 a, u32x4 b, f32x4 c) {
    return __builtin_amdgcn_mfma_f32_16x16x32_bf16(
        __builtin_bit_cast(bf16x8, a), __builtin_bit_cast(bf16x8, b), c, 0, 0, 0);
}

// pack top-16-bits of 8 floats into 4 dwords via v_perm (even elem -> low16)
__device__ __forceinline__ u32x4 packhi8(const float (&v)[8]) {
    u32x4 r;
    r.x = __builtin_amdgcn_perm(__float_as_uint(v[1]), __float_as_uint(v[0]), 0x07060302u);
    r.y = __builtin_amdgcn_perm(__float_as_uint(v[3]), __float_as_uint(v[2]), 0x07060302u);
    r.z = __builtin_amdgcn_perm(__float_as_uint(v[5]), __float_as_uint(v[4]), 0x07060302u);
    r.w = __builtin_amdgcn_perm(__float_as_uint(v[7]), __float_as_uint(v[6]), 0x07060302u);
    return r;
}

// x = s0 + s1 + s2 (truncated bf16 planes, rep err <= 2^-24 |x|)
__device__ __forceinline__ void split3_8(const float (&xv)[8],
                                         u32x4& f0, u32x4& f1, u32x4& f2) {
    float r1[8], r2[8];
#pragma unroll
    for (int j = 0; j < 8; ++j) r1[j] = xv[j] - trunc16_(xv[j]);
#pragma unroll
    for (int j = 0; j < 8; ++j) r2[j] = r1[j] - trunc16_(r1[j]);
    f0 = packhi8(xv);
    f1 = packhi8(r1);
    f2 = packhi8(r2);
}

// read 8 k-contiguous fp32 from a swizzled tile, split3
__device__ __forceinline__ void load3(const float* __restrict__ base, int tbase,
                                      int r1, int r2, u32x4& f0, u32x4& f1, u32x4& f2) {
    const f32x4 q0 = *(const f32x4*)&base[tbase + r1];
    const f32x4 q1 = *(const f32x4*)&base[tbase + r2];
    const float xv[8] = {q0.x, q0.y, q0.z, q0.w, q1.x, q1.y, q1.z, q1.w};
    split3_8(xv, f0, f1, f2);
}

// unpack b0 (hi16s) / b1 (lo16s) from 8 packed p0|p1 dwords in regs — 8 perms
__device__ __forceinline__ void unpack01r(const u32x4& d0, const u32x4& d1,
                                          u32x4& b0, u32x4& b1) {
    b0.x = __builtin_amdgcn_perm(d0.y, d0.x, 0x07060302u);
    b0.y = __builtin_amdgcn_perm(d0.w, d0.z, 0x07060302u);
    b0.z = __builtin_amdgcn_perm(d1.y, d1.x, 0x07060302u);
    b0.w = __builtin_amdgcn_perm(d1.w, d1.z, 0x07060302u);
    b1.x = __builtin_amdgcn_perm(d0.y, d0.x, 0x05040100u);
    b1.y = __builtin_amdgcn_perm(d0.w, d0.z, 0x05040100u);
    b1.z = __builtin_amdgcn_perm(d1.y, d1.x, 0x05040100u);
    b1.w = __builtin_amdgcn_perm(d1.w, d1.z, 0x05040100u);
}

__device__ __forceinline__ void loadA_all(const float* __restrict__ slab,
                                          const int (&R1v)[2], const int (&R2v)[2],
                                          u32x4 (&a0)[4][2], u32x4 (&a1)[4][2],
                                          u32x4 (&a2)[4][2]) {
#pragma unroll
    for (int ks = 0; ks < 2; ++ks)
#pragma unroll
        for (int rt = 0; rt < 4; ++rt)
            load3(slab, rt * 1024, R1v[ks], R2v[ks],
                  a0[rt][ks], a1[rt][ks], a2[rt][ks]);
}

__device__ __forceinline__ void chain6(const u32x4& A0, const u32x4& A1, const u32x4& A2,
                                       const u32x4& b0, const u32x4& b1, const u32x4& b2,
                                       f32x4& a) {
    a = mfma16(A0, b2, a);   // small terms first
    a = mfma16(A2, b0, a);
    a = mfma16(A1, b1, a);
    a = mfma16(A1, b0, a);
    a = mfma16(A0, b1, a);
    a = mfma16(A0, b0, a);
}

// mode F gemm tile: fp32 Ws + in-register split3 of B (fallback)
__device__ __forceinline__ void gemm_ct_F(const float* __restrict__ Ws, int ct,
                                          const u32x4 (&a0)[4][2], const u32x4 (&a1)[4][2],
                                          const u32x4 (&a2)[4][2],
                                          const int (&R1v)[2], const int (&R2v)[2],
                                          f32x4 (&acc)[4]) {
#pragma unroll
    for (int ks = 0; ks < 2; ++ks) {
        u32x4 b0, b1, b2;
        load3(Ws, ct * 1024, R1v[ks], R2v[ks], b0, b1, b2);
#pragma unroll
        for (int rt = 0; rt < 4; ++rt)
            chain6(a0[rt][ks], a1[rt][ks], a2[rt][ks], b0, b1, b2, acc[rt]);
    }
}

// mode G gemm tile: all 3 weight planes inline from global (L2-resident, coalesced).
// p01t/p2t include the lane*4 offset. 6 dwordx4 loads issued upfront (transient regs,
// single-tile live range — round-7 spill lesson); perms+MFMA cover the L2 latency.
__device__ __forceinline__ void gemm_ct_G(const unsigned* __restrict__ p01t,
                                          const unsigned* __restrict__ p2t,
                                          const u32x4 (&a0)[4][2], const u32x4 (&a1)[4][2],
                                          const u32x4 (&a2)[4][2],
                                          f32x4 (&acc)[4]) {
    u32x4 d0[2], d1[2], c2[2];
#pragma unroll
    for (int ks = 0; ks < 2; ++ks) {
        d0[ks] = *(const u32x4*)(p01t + ks * 512);
        d1[ks] = *(const u32x4*)(p01t + ks * 512 + 256);
        c2[ks] = *(const u32x4*)(p2t + ks * 256);
    }
#pragma unroll
    for (int ks = 0; ks < 2; ++ks) {
        u32x4 b0, b1;
        unpack01r(d0[ks], d1[ks], b0, b1);
#pragma unroll
        for (int rt = 0; rt < 4; ++rt)
            chain6(a0[rt][ks], a1[rt][ks], a2[rt][ks], b0, b1, c2[ks], acc[rt]);
    }
}

// ---- mode G dense layer (no LDS weights, no barriers) ----
template <bool RESID, bool RELU_OUT>
__device__ __forceinline__ void dense_layer_G(
    float* __restrict__ slab,
    const u32x4 (&a0)[4][2], const u32x4 (&a1)[4][2], const u32x4 (&a2)[4][2],
    const unsigned* __restrict__ p01,       // layer base, lane offset included
    const unsigned* __restrict__ p2,        // layer base, lane offset included
    const float* __restrict__ bias_g, float (&hreg)[4][4][4],
    const int (&K1)[4], const int (&K2)[4], int l15)
{
    float bly[4];
#pragma unroll
    for (int ct = 0; ct < 4; ++ct) bly[ct] = bias_g[ct * 16 + l15];
#pragma unroll
    for (int ct = 0; ct < 4; ++ct) {
        f32x4 acc[4];
#pragma unroll
        for (int rt = 0; rt < 4; ++rt) {
            if (RESID)
                acc[rt] = f32x4{hreg[rt][ct][0] + bly[ct], hreg[rt][ct][1] + bly[ct],
                                hreg[rt][ct][2] + bly[ct], hreg[rt][ct][3] + bly[ct]};
            else
                acc[rt] = f32x4{bly[ct], bly[ct], bly[ct], bly[ct]};
        }
        gemm_ct_G(p01 + ct * 1024, p2 + ct * 512, a0, a1, a2, acc);
#pragma unroll
        for (int rt = 0; rt < 4; ++rt) {
            if (RESID) {
#pragma unroll
                for (int r = 0; r < 4; ++r) hreg[rt][ct][r] = acc[rt][r];
            }
            const int base = rt * 1024 + K2[ct];
#pragma unroll
            for (int r = 0; r < 4; ++r) {
                const float v = RELU_OUT ? fmaxf(acc[rt][r], 0.0f) : acc[rt][r];
                slab[base + K1[r]] = v;
            }
        }
    }
}

// ---- h-init shared by both kernels ----
__device__ __forceinline__ void h_init_(int i, float ident, int l15, int lhi,
                                        const float* __restrict__ W_in,
                                        const float* __restrict__ b_in,
                                        u32x4 (&a0)[4][2], u32x4 (&a1)[4][2],
                                        u32x4 (&a2)[4][2], float (&hreg)[4][4][4]) {
    float idA[4], idD[4][4];
#pragma unroll
    for (int rt = 0; rt < 4; ++rt) idA[rt] = __shfl(ident, 16 * rt + l15, 64);
#pragma unroll
    for (int rt = 0; rt < 4; ++rt)
#pragma unroll
        for (int r = 0; r < 4; ++r)
            idD[rt][r] = __shfl(ident, 16 * rt + 4 * lhi + r, 64);
#pragma unroll
    for (int ks = 0; ks < 2; ++ks) {
        const int kb = i * 64 + 32 * ks + 8 * lhi;
        const f32x4 w0 = *(const f32x4*)&W_in[kb];
        const f32x4 w1 = *(const f32x4*)&W_in[kb + 4];
        const f32x4 c0 = *(const f32x4*)&b_in[kb];
        const f32x4 c1 = *(const f32x4*)&b_in[kb + 4];
        const float wv[8] = {w0.x, w0.y, w0.z, w0.w, w1.x, w1.y, w1.z, w1.w};
        const float bv[8] = {c0.x, c0.y, c0.z, c0.w, c1.x, c1.y, c1.z, c1.w};
#pragma unroll
        for (int rt = 0; rt < 4; ++rt) {
            float hx[8];
#pragma unroll
            for (int j = 0; j < 8; ++j)
                hx[j] = fmaxf(fmaf(idA[rt], wv[j], bv[j]), 0.0f);
            split3_8(hx, a0[rt][ks], a1[rt][ks], a2[rt][ks]);
        }
    }
#pragma unroll
    for (int ct = 0; ct < 4; ++ct) {
        const float wD = W_in[i * 64 + ct * 16 + l15];
        const float bD = b_in[i * 64 + ct * 16 + l15];
#pragma unroll
        for (int rt = 0; rt < 4; ++rt)
#pragma unroll
            for (int r = 0; r < 4; ++r)
                hreg[rt][ct][r] = fmaf(idD[rt][r], wD, bD);
    }
}

// ================== mode G kernel: 1 wave/block, ZERO barriers ==================
// Round-10 post-mortem: __launch_bounds__(64,3) capped VGPR at 84 -> ~220 live
// values spilled to scratch (WRITE_SIZE 3.8 GB). (64,2) caps at 256 >= need;
// occupancy 2 waves/SIMD = 8 waves/CU = round-9 parity, but zero barriers.
__global__ __launch_bounds__(64, 2) void nsf_g(
    const float* __restrict__ x,
    const float* __restrict__ W_in,  const float* __restrict__ b_in,
    const float* __restrict__ b_blk, const float* __restrict__ b_out,
    const float* __restrict__ wt,
    float* __restrict__ out, int n)
{
    __shared__ __align__(16) float slab[4096];   // 16 KB

    const int wl  = threadIdx.x;   // 0..63
    const int l15 = wl & 15;
    const int lhi = wl >> 4;

    const int gidx = blockIdx.x * 64 + wl;
    const int idx  = gidx < n ? gidx : (n - 1);

    float z0 = x[3 * idx + 0];
    float z1 = x[3 * idx + 1];
    float z2 = x[3 * idx + 2];
    float lad_total = 0.0f;

    // lane-constant addresses. slab dword(p,k) = p*64 + ((k>>2 ^ (p&15))<<2) + (k&3)
    int K1[4], K2[4], R1v[2], R2v[2], P1[4];
#pragma unroll
    for (int r = 0; r < 4; ++r)
        K1[r] = (4 * lhi + r) * 64 + ((((l15 >> 2) ^ r)) << 2) + (l15 & 3);
#pragma unroll
    for (int c = 0; c < 4; ++c) K2[c] = (c ^ lhi) << 4;
#pragma unroll
    for (int s = 0; s < 2; ++s) {
        const int c0 = 8 * s + 2 * lhi;
        R1v[s] = l15 * 64 + ((c0 ^ l15) << 2);
        R2v[s] = l15 * 64 + (((c0 + 1) ^ l15) << 2);
    }
#pragma unroll
    for (int r = 0; r < 4; ++r) P1[r] = (4 * lhi + r) * PPP_ + l15;

    // global weight-plane bases for this lane
    const unsigned* b01w  = (const unsigned*)wt +           wl * 4;
    const unsigned* p2w   = (const unsigned*)wt + P2B_    + wl * 4;
    const unsigned* hb01w = (const unsigned*)wt + HEAD_PB + wl * 4;
    const unsigned* hp2w  = (const unsigned*)wt + HP2B_   + wl * 4;

#pragma unroll 1
    for (int i = 0; i < NT_; ++i) {
        const float ident = z2, tr0 = z1, tr1 = z0;

        u32x4 a0[4][2], a1[4][2], a2[4][2];
        float hreg[4][4][4];
        h_init_(i, ident, l15, lhi, W_in, b_in, a0, a1, a2, hreg);

        // G1..G4, no barriers: slab is wave-private; weights stream from L2
        dense_layer_G<false, true>(slab, a0, a1, a2,
                                   b01w + (size_t)(i * 4 + 0) * 4096,
                                   p2w  + (size_t)(i * 4 + 0) * 2048,
                                   b_blk + (size_t)(i * 4 + 0) * 64, hreg, K1, K2, l15);
        loadA_all(slab, R1v, R2v, a0, a1, a2);               // A2 = relu(t1)
        dense_layer_G<true, true>(slab, a0, a1, a2,
                                  b01w + (size_t)(i * 4 + 1) * 4096,
                                  p2w  + (size_t)(i * 4 + 1) * 2048,
                                  b_blk + (size_t)(i * 4 + 1) * 64, hreg, K1, K2, l15);
        loadA_all(slab, R1v, R2v, a0, a1, a2);               // A3 = relu(h1)
        dense_layer_G<false, true>(slab, a0, a1, a2,
                                   b01w + (size_t)(i * 4 + 2) * 4096,
                                   p2w  + (size_t)(i * 4 + 2) * 2048,
                                   b_blk + (size_t)(i * 4 + 2) * 64, hreg, K1, K2, l15);
        loadA_all(slab, R1v, R2v, a0, a1, a2);               // A4 = relu(t3)
        dense_layer_G<true, false>(slab, a0, a1, a2,
                                   b01w + (size_t)(i * 4 + 3) * 4096,
                                   p2w  + (size_t)(i * 4 + 3) * 2048,
                                   b_blk + (size_t)(i * 4 + 3) * 64, hreg, K1, K2, l15);
        loadA_all(slab, R1v, R2v, a0, a1, a2);               // A5 = raw h2

        const unsigned* hb01 = hb01w + (size_t)i * 5120;
        const unsigned* hp2  = hp2w  + (size_t)i * 2560;

        // ---- head half 0: ct0, ct1 -> params; comb (ctg2) -> regs ----
        f32x4 combD[4];
#pragma unroll
        for (int ct = 0; ct < 3; ++ct) {
            f32x4 acc[4];
#pragma unroll
            for (int rt = 0; rt < 4; ++rt) acc[rt] = f32x4{0.f, 0.f, 0.f, 0.f};
            gemm_ct_G(hb01 + ct * 1024, hp2 + ct * 512, a0, a1, a2, acc);
            if (ct < 2) {
#pragma unroll
                for (int rt = 0; rt < 4; ++rt)
#pragma unroll
                    for (int r = 0; r < 4; ++r)
                        slab[rt * 656 + P1[r] + 16 * ct] = acc[rt][r];
            } else {
#pragma unroll
                for (int rt = 0; rt < 4; ++rt) combD[rt] = acc[rt];
                if (l15 < 5) {
#pragma unroll
                    for (int rt = 0; rt < 4; ++rt)
#pragma unroll
                        for (int r = 0; r < 4; ++r)
                            slab[rt * 656 + P1[r] + 32] = acc[rt][r];
                }
            }
        }

        const float* bo = b_out + i * 74;
        float y0, l0v, y1, l1v;
        {
            float p0[37];
#pragma unroll
            for (int q = 0; q < 37; ++q) p0[q] = slab[wl * PPP_ + q] + bo[q];
            rq_spline_reg(p0, tr0, y0, l0v);
        }

        // ---- head half 1: ctg 3,4 + saved comb cols ----
#pragma unroll
        for (int ct = 0; ct < 2; ++ct) {
            f32x4 acc[4];
#pragma unroll
            for (int rt = 0; rt < 4; ++rt) acc[rt] = f32x4{0.f, 0.f, 0.f, 0.f};
            gemm_ct_G(hb01 + (3 + ct) * 1024, hp2 + (3 + ct) * 512, a0, a1, a2, acc);
#pragma unroll
            for (int rt = 0; rt < 4; ++rt)
#pragma unroll
                for (int r = 0; r < 4; ++r)
                    slab[rt * 656 + P1[r] + 16 * ct] = acc[rt][r];
        }
        if (l15 >= 8 && l15 < 13) {
#pragma unroll
            for (int rt = 0; rt < 4; ++rt)
#pragma unroll
                for (int r = 0; r < 4; ++r)
                    slab[rt * 656 + P1[r] + 24] = combD[rt][r];  // q = 32 + (l15-8)
        }
        {
            float p1[37];
#pragma unroll
            for (int q = 0; q < 37; ++q) p1[q] = slab[wl * PPP_ + q] + bo[37 + q];
            rq_spline_reg(p1, tr1, y1, l1v);
        }

        lad_total += l0v + l1v;
        z0 = ident;
        z1 = y0;
        z2 = y1;
    }

    if (gidx < n)
        out[gidx] = -0.5f * (z0 * z0 + z1 * z1 + z2 * z2) + LOGZ_ + lad_total;
}

// ================== mode F fallback kernel (round-9 P=false, verbatim) ==================
template <bool RESID, bool RELU_OUT>
__device__ __forceinline__ void dense_layer_F(
    float* __restrict__ slab, const float* __restrict__ Ws,
    const u32x4 (&a0)[4][2], const u32x4 (&a1)[4][2], const u32x4 (&a2)[4][2],
    const int (&R1v)[2], const int (&R2v)[2],
    const float* __restrict__ bias_g, float (&hreg)[4][4][4],
    const int (&K1)[4], const int (&K2)[4], int l15)
{
    float bly[4];
#pragma unroll
    for (int ct = 0; ct < 4; ++ct) bly[ct] = bias_g[ct * 16 + l15];
#pragma unroll
    for (int ct = 0; ct < 4; ++ct) {
        f32x4 acc[4];
#pragma unroll
        for (int rt = 0; rt < 4; ++rt) {
            if (RESID)
                acc[rt] = f32x4{hreg[rt][ct][0] + bly[ct], hreg[rt][ct][1] + bly[ct],
                                hreg[rt][ct][2] + bly[ct], hreg[rt][ct][3] + bly[ct]};
            else
                acc[rt] = f32x4{bly[ct], bly[ct], bly[ct], bly[ct]};
        }
        gemm_ct_F(Ws, ct, a0, a1, a2, R1v, R2v, acc);
#pragma unroll
        for (int rt = 0; rt < 4; ++rt) {
            if (RESID) {
#pragma unroll
                for (int r = 0; r < 4; ++r) hreg[rt][ct][r] = acc[rt][r];
            }
            const int base = rt * 1024 + K2[ct];
#pragma unroll
            for (int r = 0; r < 4; ++r) {
                const float v = RELU_OUT ? fmaxf(acc[rt][r], 0.0f) : acc[rt][r];
                slab[base + K1[r]] = v;
            }
        }
    }
}

__global__ __launch_bounds__(256, 2) void nsf_f(
    const float* __restrict__ x,
    const float* __restrict__ W_in,  const float* __restrict__ b_in,
    const float* __restrict__ b_blk, const float* __restrict__ b_out,
    const float* __restrict__ wt,
    float* __restrict__ out, int n)
{
    __shared__ __align__(16) float As2[WAVES_ * 4096];
    __shared__ __align__(16) float Ws[4096];

    const int l    = threadIdx.x;
    const int wave = l >> 6;
    const int wl   = l & 63;
    const int l15  = wl & 15;
    const int lhi  = wl >> 4;
    float* slab = As2 + wave * 4096;

    const int gidx = blockIdx.x * 256 + l;
    const int idx  = gidx < n ? gidx : (n - 1);

    float z0 = x[3 * idx + 0];
    float z1 = x[3 * idx + 1];
    float z2 = x[3 * idx + 2];
    float lad_total = 0.0f;

    int K1[4], K2[4], R1v[2], R2v[2], P1[4];
#pragma unroll
    for (int r = 0; r < 4; ++r)
        K1[r] = (4 * lhi + r) * 64 + ((((l15 >> 2) ^ r)) << 2) + (l15 & 3);
#pragma unroll
    for (int c = 0; c < 4; ++c) K2[c] = (c ^ lhi) << 4;
#pragma unroll
    for (int s = 0; s < 2; ++s) {
        const int c0 = 8 * s + 2 * lhi;
        R1v[s] = l15 * 64 + ((c0 ^ l15) << 2);
        R2v[s] = l15 * 64 + (((c0 + 1) ^ l15) << 2);
    }
#pragma unroll
    for (int r = 0; r < 4; ++r) P1[r] = (4 * lhi + r) * PPP_ + l15;

    stage_<16>(wt, Ws, wave, wl);
    __syncthreads();

#pragma unroll 1
    for (int i = 0; i < NT_; ++i) {
        const float ident = z2, tr0 = z1, tr1 = z0;

        u32x4 a0[4][2], a1[4][2], a2[4][2];
        float hreg[4][4][4];
        h_init_(i, ident, l15, lhi, W_in, b_in, a0, a1, a2, hreg);

        dense_layer_F<false, true>(slab, Ws, a0, a1, a2, R1v, R2v,
                                   b_blk + (size_t)(i * 4 + 0) * 64, hreg, K1, K2, l15);
        __syncthreads();
        stage_<16>(wt + (size_t)(i * 4 + 1) * 4096, Ws, wave, wl);
        loadA_all(slab, R1v, R2v, a0, a1, a2);
        __syncthreads();

        dense_layer_F<true, true>(slab, Ws, a0, a1, a2, R1v, R2v,
                                  b_blk + (size_t)(i * 4 + 1) * 64, hreg, K1, K2, l15);
        __syncthreads();
        stage_<16>(wt + (size_t)(i * 4 + 2) * 4096, Ws, wave, wl);
        loadA_all(slab, R1v, R2v, a0, a1, a2);
        __syncthreads();

        dense_layer_F<false, true>(slab, Ws, a0, a1, a2, R1v, R2v,
                                   b_blk + (size_t)(i * 4 + 2) * 64, hreg, K1, K2, l15);
        __syncthreads();
        stage_<16>(wt + (size_t)(i * 4 + 3) * 4096, Ws, wave, wl);
        loadA_all(slab, R1v, R2v, a0, a1, a2);
        __syncthreads();

        dense_layer_F<true, false>(slab, Ws, a0, a1, a2, R1v, R2v,
                                   b_blk + (size_t)(i * 4 + 3) * 64, hreg, K1, K2, l15);
        __syncthreads();
        stage_<12>(wt + HEAD_FB + (size_t)i * 5120, Ws, wave, wl);
        loadA_all(slab, R1v, R2v, a0, a1, a2);
        __syncthreads();

        f32x4 combD[4];
#pragma unroll
        for (int ct = 0; ct < 3; ++ct) {
            f32x4 acc[4];
#pragma unroll
            for (int rt = 0; rt < 4; ++rt) acc[rt] = f32x4{0.f, 0.f, 0.f, 0.f};
            gemm_ct_F(Ws, ct, a0, a1, a2, R1v, R2v, acc);
            if (ct < 2) {
#pragma unroll
                for (int rt = 0; rt < 4; ++rt)
#pragma unroll
                    for (int r = 0; r < 4; ++r)
                        slab[rt * 656 + P1[r] + 16 * ct] = acc[rt][r];
            } else {
#pragma unroll
                for (int rt = 0; rt < 4; ++rt) combD[rt] = acc[rt];
                if (l15 < 5) {
#pragma unroll
                    for (int rt = 0; rt < 4; ++rt)
#pragma unroll
                        for (int r = 0; r < 4; ++r)
                            slab[rt * 656 + P1[r] + 32] = acc[rt][r];
                }
            }
        }
        __syncthreads();
        stage_<8>(wt + HEAD_FB + (size_t)i * 5120 + 3072, Ws, wave, wl);

        const float* bo = b_out + i * 74;
        float y0, l0v, y1, l1v;
        {
            float p0[37];
#pragma unroll
            for (int q = 0; q < 37; ++q) p0[q] = slab[wl * PPP_ + q] + bo[q];
            rq_spline_reg(p0, tr0, y0, l0v);
        }
        __syncthreads();

#pragma unroll
        for (int ct = 0; ct < 2; ++ct) {
            f32x4 acc[4];
#pragma unroll
            for (int rt = 0; rt < 4; ++rt) acc[rt] = f32x4{0.f, 0.f, 0.f, 0.f};
            gemm_ct_F(Ws, ct, a0, a1, a2, R1v, R2v, acc);
#pragma unroll
            for (int rt = 0; rt < 4; ++rt)
#pragma unroll
                for (int r = 0; r < 4; ++r)
                    slab[rt * 656 + P1[r] + 16 * ct] = acc[rt][r];
        }
        if (l15 >= 8 && l15 < 13) {
#pragma unroll
            for (int rt = 0; rt < 4; ++rt)
#pragma unroll
                for (int r = 0; r < 4; ++r)
                    slab[rt * 656 + P1[r] + 24] = combD[rt][r];
        }
        __syncthreads();
        if (i < NT_ - 1) stage_<16>(wt + (size_t)((i + 1) * 4) * 4096, Ws, wave, wl);
        {
            float p1[37];
#pragma unroll
            for (int q = 0; q < 37; ++q) p1[q] = slab[wl * PPP_ + q] + bo[37 + q];
            rq_spline_reg(p1, tr1, y1, l1v);
        }
        __syncthreads();

        lad_total += l0v + l1v;
        z0 = ident;
        z1 = y0;
        z2 = y1;
    }

    if (gidx < n)
        out[gidx] = -0.5f * (z0 * z0 + z1 * z1 + z2 * z2) + LOGZ_ + lad_total;
}

}  // namespace

extern "C" void kernel_launch(void* const* d_in, const int* in_sizes, int n_in,
                              void* d_out, int out_size, void* d_ws, size_t ws_size,
                              hipStream_t stream) {
    const float* x     = (const float*)d_in[0];
    const float* W_in  = (const float*)d_in[1];
    const float* b_in  = (const float*)d_in[2];
    const float* W_blk = (const float*)d_in[3];
    const float* b_blk = (const float*)d_in[4];
    const float* W_out = (const float*)d_in[5];
    const float* b_out = (const float*)d_in[6];
    float* out = (float*)d_out;

    const int n = in_sizes[0] / 3;

    if (ws_size >= WS_P_BYTES) {
        prep_G<<<(PREP_TOT_P + 255) / 256, 256, 0, stream>>>(
            W_blk, W_out, (float*)d_ws);
        const int grid = (n + 63) / 64;
        nsf_g<<<grid, 64, 0, stream>>>(x, W_in, b_in, b_blk, b_out,
                                       (const float*)d_ws, out, n);
    } else {
        prep_F<<<(PREP_TOT_F + 255) / 256, 256, 0, stream>>>(
            W_blk, W_out, (float*)d_ws);
        const int grid = (n + 255) / 256;
        nsf_f<<<grid, 256, 0, stream>>>(x, W_in, b_in, b_blk, b_out,
                                        (const float*)d_ws, out, n);
    }
}